// Round 8
// baseline (569.560 us; speedup 1.0000x reference)
//
#include <hip/hip_runtime.h>
#include <hip/hip_bf16.h>
#include <stdint.h>

// Problem dims
#define BATCH 256
#define SEQ   512
#define INDIM 64
#define H     128
#define RB    4               // batch rows per block (valid C-rows at quad*4, r=0)
#define NTILE (BATCH / RB)    // 64 batch tiles per layer
#define CH    16              // pipeline handoff chunk (steps)
#define NCH   (SEQ / CH)

using short8  = __attribute__((ext_vector_type(8))) short;  // 8 bf16 MFMA A/B frag
using float4v = __attribute__((ext_vector_type(4))) float;  // MFMA C/D frag

#define LOG2E 1.4426950408889634f

__device__ __forceinline__ unsigned short f2bf(float f) {
    union { float f; uint32_t u; } v; v.f = f;
    uint32_t u = v.u;
    return (unsigned short)((u + 0x7FFFu + ((u >> 16) & 1u)) >> 16); // RNE
}

__device__ __forceinline__ float fast_exp2(float x) {
#if __has_builtin(__builtin_amdgcn_exp2f)
    return __builtin_amdgcn_exp2f(x);
#else
    return __expf(x * 0.6931471805599453f);
#endif
}
__device__ __forceinline__ float fast_rcp(float x) {
#if __has_builtin(__builtin_amdgcn_rcpf)
    return __builtin_amdgcn_rcpf(x);
#else
    return 1.f / x;
#endif
}
__device__ __forceinline__ float sigmoid_fast(float x) {
    return fast_rcp(1.f + fast_exp2(-LOG2E * x));
}
__device__ __forceinline__ float tanh_fast(float x) {
    return fmaf(-2.f, fast_rcp(1.f + fast_exp2((2.f * LOG2E) * x)), 1.f);
}

// In-step barrier: LDS ordering only (lgkmcnt). Global prefetch loads and
// producer h-stores stay in flight across it. Full __syncthreads (vmcnt
// drain) only at producer chunk boundaries.
__device__ __forceinline__ void light_barrier() {
    asm volatile("s_waitcnt lgkmcnt(0)\n\ts_barrier" ::: "memory");
}

// Load 8 consecutive f32 and pack to bf16 (RNE, identical to f2bf).
// Used by the producer to consume x directly in f32 (conv kernel deleted).
__device__ __forceinline__ short8 ldcvt8(const float* p) {
    float4 a = *(const float4*)p;
    float4 b = *(const float4*)(p + 4);
    union { uint32_t w[4]; short8 s; } u;
    asm("v_cvt_pk_bf16_f32 %0, %1, %2" : "=v"(u.w[0]) : "v"(a.x), "v"(a.y));
    asm("v_cvt_pk_bf16_f32 %0, %1, %2" : "=v"(u.w[1]) : "v"(a.z), "v"(a.w));
    asm("v_cvt_pk_bf16_f32 %0, %1, %2" : "=v"(u.w[2]) : "v"(b.x), "v"(b.y));
    asm("v_cvt_pk_bf16_f32 %0, %1, %2" : "=v"(u.w[3]) : "v"(b.z), "v"(b.w));
    return u.s;
}

// ---------------- fused 2-layer pipelined LSTM + head ----------------
// 128 blocks x 512 threads (R5 skeleton = 407-410us verified). Blocks
// 0..63: layer0 (producer, reads x f32 directly), 64..127: layer1
// (consumer), paired on batch tile bt via chunked flag handoff over h0sq.
//
// Established model (R7 post-mortem): per-SIMD MFMA throughput is ~16cy per
// 16x16x32 -> consumer step = 2 waves x 32 MFMA x 16 = ~1030cy mandatory
// pipe time + ~800cy unhidden latency (ds_read, dep chains, activation
// tail). R2/R7: occupancy and wave-width moves are dead; the lever is
// filling the latency windows with MFMA work.
//
// R8 changes vs R5:
//  (1) consumer split-pipeline: x-proj kt{2,3} of x(t) at step start (fills
//      ds_read window, as before); x-proj kt{0,1} of x(t+1) issues AFTER
//      gate extraction, DURING the activation chain (VALU/trans - MFMA pipe
//      was idle there). Partial acc pA = bias + x0 + x1 persists across the
//      barrier (+16 regs). Gate math order unchanged -> bit-identical.
//  (2) conv_x_kernel deleted: producer loads x as f32 and packs via
//      v_cvt_pk_bf16_f32 (RNE = f2bf) in the prefetch path (off critical
//      path; producer has MFMA slack: 24 vs consumer 32). Flags zeroed by
//      hipMemsetAsync. Saves a launch + the serial conv->lstm dependency.
// R4 lesson kept: consumer x reload distance stays ~2 steps (cross-CU h0sq
// reads need the latency cover). R5 lesson kept: all register arrays
// statically indexed; double buffers statically named.
template<int KIN, bool IS_PROD>
__device__ __forceinline__ void lstm_body(
    const float* __restrict__ xf32,          // producer input: [BATCH][SEQ][KIN] f32
    const unsigned short* __restrict__ xbf,  // consumer input: [BATCH][SEQ][KIN] bf16
    const float* __restrict__ Wih,           // [4H][KIN]
    const float* __restrict__ Whh,           // [4H][H]
    const float* __restrict__ b_ih, const float* __restrict__ b_hh,
    unsigned short* __restrict__ outseq,     // producer: [BATCH][SEQ][H] bf16
    const float* __restrict__ W1, const float* __restrict__ b1,
    const float* __restrict__ W2, const float* __restrict__ b2,
    float* __restrict__ out,                 // consumer: [BATCH][3]
    int* flag, int bt)
{
    constexpr int KT  = KIN / 32;
    constexpr int PAD = 132;                 // 66 dwords == 2 mod 32 -> 2-way (free) aliasing
    const int lane = threadIdx.x & 63;
    const int quad = lane >> 4;
    const int l16  = lane & 15;
    const int b0   = bt * RB;
    const int cell = (threadIdx.x >> 6) * 16 + l16;
    const int arow = l16 & 12;               // LDS h row this lane reads (4-lane broadcast)
    const int xrow = b0 + (l16 >> 2);        // batch row this lane loads (duplicated 4x)

    __shared__ short hbuf[2][16][PAD];
    __shared__ float hl[RB][128];            // fp32 h_last (consumer head input)
    __shared__ float mid[RB][65];
    for (int i = threadIdx.x; i < 2 * 16 * PAD; i += 512) ((short*)hbuf)[i] = 0;

    // ---- weight fragments (loaded once, fp32->bf16, persist in registers) ----
    short8 whh_f[4][4];
    short8 wih_f[4][KT];
    float  bias[4];
#pragma unroll
    for (int tT = 0; tT < 4; tT++) {
        const int n = tT * 128 + cell;
#pragma unroll
        for (int kt = 0; kt < 4; kt++) {
            const float* p = Whh + (size_t)n * H + kt * 32 + quad * 8;
            float4 f0 = *(const float4*)p;
            float4 f1 = *(const float4*)(p + 4);
            short8 s;
            s[0]=f2bf(f0.x); s[1]=f2bf(f0.y); s[2]=f2bf(f0.z); s[3]=f2bf(f0.w);
            s[4]=f2bf(f1.x); s[5]=f2bf(f1.y); s[6]=f2bf(f1.z); s[7]=f2bf(f1.w);
            whh_f[tT][kt] = s;
        }
#pragma unroll
        for (int kt = 0; kt < KT; kt++) {
            const float* p = Wih + (size_t)n * KIN + kt * 32 + quad * 8;
            float4 f0 = *(const float4*)p;
            float4 f1 = *(const float4*)(p + 4);
            short8 s;
            s[0]=f2bf(f0.x); s[1]=f2bf(f0.y); s[2]=f2bf(f0.z); s[3]=f2bf(f0.w);
            s[4]=f2bf(f1.x); s[5]=f2bf(f1.y); s[6]=f2bf(f1.z); s[7]=f2bf(f1.w);
            wih_f[tT][kt] = s;
        }
        bias[tT] = b_ih[n] + b_hh[n];
    }

    // ---- persistent seed registers (R5) ----
    float4v bias4[4], zero4;
#pragma unroll
    for (int tT = 0; tT < 4; tT++)
        bias4[tT] = (float4v){bias[tT], bias[tT], bias[tT], bias[tT]};
    zero4 = (float4v){0.f, 0.f, 0.f, 0.f};
    asm volatile("" : "+v"(bias4[0]), "+v"(bias4[1]), "+v"(bias4[2]),
                      "+v"(bias4[3]), "+v"(zero4));

    float c0 = 0.f;                          // this lane's single cell state

    const float* xpf = nullptr;
    const unsigned short* xpb = nullptr;
    if constexpr (IS_PROD)
        xpf = xf32 + ((size_t)xrow * SEQ) * KIN + quad * 8;
    else
        xpb = xbf + ((size_t)xrow * SEQ) * KIN + quad * 8;
    unsigned short* op = nullptr;
    if (IS_PROD)
        op = outseq + ((size_t)(b0 + quad) * SEQ) * H + cell;

    short8 xf0[KT], xf1[KT];                 // statically-named x double buffer
    __syncthreads();                         // hbuf zero-init visible

    if constexpr (IS_PROD) {
        // ================= producer: R5 step verbatim (f32 x loads) ========
        auto pstep = [&](int t, int CUR, short8 (&xf)[KT],
                         bool doPre) __attribute__((always_inline)) {
            short8 ha[4];
#pragma unroll
            for (int kt = 0; kt < 4; kt++)
                ha[kt] = *(const short8*)&hbuf[CUR][arow][kt * 32 + quad * 8];

            float4v accA[4], accB[4];
#pragma unroll
            for (int tT = 0; tT < 4; tT++)
                accA[tT] = __builtin_amdgcn_mfma_f32_16x16x32_bf16(xf[0], wih_f[tT][0], bias4[tT], 0, 0, 0);
#pragma unroll
            for (int tT = 0; tT < 4; tT++)
                accA[tT] = __builtin_amdgcn_mfma_f32_16x16x32_bf16(xf[1], wih_f[tT][1], accA[tT], 0, 0, 0);
            if (doPre) {                     // reload xf = x(t+2) (WAR after use)
                const float* p = xpf + (size_t)(t + 2) * KIN;
#pragma unroll
                for (int kt = 0; kt < KT; kt++) xf[kt] = ldcvt8(p + kt * 32);
            }
#pragma unroll
            for (int tT = 0; tT < 4; tT++)
                accA[tT] = __builtin_amdgcn_mfma_f32_16x16x32_bf16(ha[0], whh_f[tT][0], accA[tT], 0, 0, 0);
#pragma unroll
            for (int tT = 0; tT < 4; tT++)
                accB[tT] = __builtin_amdgcn_mfma_f32_16x16x32_bf16(ha[2], whh_f[tT][2], zero4, 0, 0, 0);
#pragma unroll
            for (int tT = 0; tT < 4; tT++)
                accA[tT] = __builtin_amdgcn_mfma_f32_16x16x32_bf16(ha[1], whh_f[tT][1], accA[tT], 0, 0, 0);
#pragma unroll
            for (int tT = 0; tT < 4; tT++)
                accB[tT] = __builtin_amdgcn_mfma_f32_16x16x32_bf16(ha[3], whh_f[tT][3], accB[tT], 0, 0, 0);

            float g0 = accA[0][0] + accB[0][0];
            float g1 = accA[1][0] + accB[1][0];
            float g2 = accA[2][0] + accB[2][0];
            float g3 = accA[3][0] + accB[3][0];

            float si = sigmoid_fast(g0);
            float sf = sigmoid_fast(g1);
            float tg = tanh_fast(g2);
            float so = sigmoid_fast(g3);
            c0 = fmaf(sf, c0, si * tg);
            float h = so * tanh_fast(c0);
            uint32_t hp;
            asm("v_cvt_pk_bf16_f32 %0, %1, %2" : "=v"(hp) : "v"(h), "v"(h));
            hbuf[CUR ^ 1][quad * 4][cell] = (short)(hp & 0xffffu);
            *op = (unsigned short)(hp & 0xffffu);  // fire-and-forget; drained at chunk end
            op += H;
            light_barrier();
        };

        // one-time fill: x(0), x(1) (converted inline)
#pragma unroll
        for (int kt = 0; kt < KT; kt++) {
            xf0[kt] = ldcvt8(xpf + kt * 32);
            xf1[kt] = ldcvt8(xpf + KIN + kt * 32);
        }
        for (int ch = 0; ch < NCH; ch++) {
            const int t0 = ch * CH;
#pragma unroll 1
            for (int i = 0; i < CH; i += 2) {
                const int t = t0 + i;
                pstep(t,     0, xf0, t + 2 < SEQ);
                pstep(t + 1, 1, xf1, t + 3 < SEQ);
            }
            __syncthreads();                 // vmcnt drain (h0sq stores) for release
            if (threadIdx.x == 0)
                __hip_atomic_fetch_add(flag, 1, __ATOMIC_RELEASE, __HIP_MEMORY_SCOPE_AGENT);
        }
    } else {
        // ================= consumer: split-pipeline step (R8) ==============
        // pA persists across the barrier: bias + x0 + x1 of the NEXT step,
        // computed during the activation tail while the MFMA pipe is idle.
        float4v pA[4];

        // cstep(t): on entry pA = bias + x0(t) + x1(t).
        //   accB = x2(t) + x3(t)            (fills ds_read window)
        //   reload xfC <- x(t+2)            (WAR; ~1.4 steps to first use)
        //   pA  += h0 + h1 ; accB += h2 + h3 (depth-2 chains)
        //   g = pA[0] + accB[0]
        //   pA = bias + x0(t+1) + x1(t+1)   (DURING activation -> pipe fed)
        //   act, cvt, ds_write, barrier
        auto cstep = [&](int t, int CUR, short8 (&xfC)[KT], short8 (&xfN)[KT],
                         bool doPre, bool doNext) __attribute__((always_inline)) {
            short8 ha[4];
#pragma unroll
            for (int kt = 0; kt < 4; kt++)
                ha[kt] = *(const short8*)&hbuf[CUR][arow][kt * 32 + quad * 8];

            float4v accB[4];
#pragma unroll
            for (int tT = 0; tT < 4; tT++)
                accB[tT] = __builtin_amdgcn_mfma_f32_16x16x32_bf16(xfC[2], wih_f[tT][2], zero4, 0, 0, 0);
#pragma unroll
            for (int tT = 0; tT < 4; tT++)
                accB[tT] = __builtin_amdgcn_mfma_f32_16x16x32_bf16(xfC[3], wih_f[tT][3], accB[tT], 0, 0, 0);
            if (doPre) {                     // reload xfC = x(t+2) (WAR after use)
                const unsigned short* p = xpb + (size_t)(t + 2) * KIN;
#pragma unroll
                for (int kt = 0; kt < KT; kt++) xfC[kt] = *(const short8*)(p + kt * 32);
            }
            // recurrent projection: two parallel depth-2 chains
#pragma unroll
            for (int tT = 0; tT < 4; tT++)
                pA[tT] = __builtin_amdgcn_mfma_f32_16x16x32_bf16(ha[0], whh_f[tT][0], pA[tT], 0, 0, 0);
#pragma unroll
            for (int tT = 0; tT < 4; tT++)
                accB[tT] = __builtin_amdgcn_mfma_f32_16x16x32_bf16(ha[2], whh_f[tT][2], accB[tT], 0, 0, 0);
#pragma unroll
            for (int tT = 0; tT < 4; tT++)
                pA[tT] = __builtin_amdgcn_mfma_f32_16x16x32_bf16(ha[1], whh_f[tT][1], pA[tT], 0, 0, 0);
#pragma unroll
            for (int tT = 0; tT < 4; tT++)
                accB[tT] = __builtin_amdgcn_mfma_f32_16x16x32_bf16(ha[3], whh_f[tT][3], accB[tT], 0, 0, 0);

            float g0 = pA[0][0] + accB[0][0];
            float g1 = pA[1][0] + accB[1][0];
            float g2 = pA[2][0] + accB[2][0];
            float g3 = pA[3][0] + accB[3][0];

            // refill pA for t+1 NOW: these 8 MFMAs run under the activation
            if (doNext) {
#pragma unroll
                for (int tT = 0; tT < 4; tT++)
                    pA[tT] = __builtin_amdgcn_mfma_f32_16x16x32_bf16(xfN[0], wih_f[tT][0], bias4[tT], 0, 0, 0);
#pragma unroll
                for (int tT = 0; tT < 4; tT++)
                    pA[tT] = __builtin_amdgcn_mfma_f32_16x16x32_bf16(xfN[1], wih_f[tT][1], pA[tT], 0, 0, 0);
            }

            float si = sigmoid_fast(g0);
            float sf = sigmoid_fast(g1);
            float tg = tanh_fast(g2);
            float so = sigmoid_fast(g3);
            c0 = fmaf(sf, c0, si * tg);
            float h = so * tanh_fast(c0);
            uint32_t hp;
            asm("v_cvt_pk_bf16_f32 %0, %1, %2" : "=v"(hp) : "v"(h), "v"(h));
            hbuf[CUR ^ 1][quad * 4][cell] = (short)(hp & 0xffffu);
            if (t == SEQ - 1) hl[quad][cell] = h;
            light_barrier();
        };

        for (int ch = 0; ch < NCH; ch++) {
            const int t0 = ch * CH;
            if (threadIdx.x == 0) {
                while (__hip_atomic_load(flag, __ATOMIC_RELAXED, __HIP_MEMORY_SCOPE_AGENT) <= ch)
                    __builtin_amdgcn_s_sleep(2);
                (void)__hip_atomic_load(flag, __ATOMIC_ACQUIRE, __HIP_MEMORY_SCOPE_AGENT);
            }
            __syncthreads();
            // chunk fill: x(t0), x(t0+1) + recompute pA for step t0
            {
                const unsigned short* p0 = xpb + (size_t)t0 * KIN;
                const unsigned short* p1 = p0 + KIN;
#pragma unroll
                for (int kt = 0; kt < KT; kt++) {
                    xf0[kt] = *(const short8*)(p0 + kt * 32);
                    xf1[kt] = *(const short8*)(p1 + kt * 32);
                }
#pragma unroll
                for (int tT = 0; tT < 4; tT++)
                    pA[tT] = __builtin_amdgcn_mfma_f32_16x16x32_bf16(xf0[0], wih_f[tT][0], bias4[tT], 0, 0, 0);
#pragma unroll
                for (int tT = 0; tT < 4; tT++)
                    pA[tT] = __builtin_amdgcn_mfma_f32_16x16x32_bf16(xf0[1], wih_f[tT][1], pA[tT], 0, 0, 0);
            }

#pragma unroll 1
            for (int i = 0; i < CH; i += 2) {
                const int t = t0 + i;
                // even step: xfC=xf0 (x(t)), xfN=xf1 (x(t+1), always in-chunk)
                cstep(t,     0, xf0, xf1, i + 2 < CH, true);
                // odd step: xfC=xf1 (x(t+1)), xfN=xf0 (x(t+2) if reloaded)
                cstep(t + 1, 1, xf1, xf0, i + 3 < CH, i + 2 < CH);
            }
        }

        // ---- MLP head for this block's RB rows (hl visible via last barrier)
        if (threadIdx.x < RB * 64) {
            const int row = threadIdx.x >> 6, j = threadIdx.x & 63;
            float s = b1[j];
            const float* wr = W1 + (size_t)j * 128;
#pragma unroll 8
            for (int k = 0; k < 128; k++) s = fmaf(hl[row][k], wr[k], s);
            mid[row][j] = fmaxf(s, 0.f);
        }
        __syncthreads();
        if (threadIdx.x < RB * 3) {
            const int row = threadIdx.x / 3, k = threadIdx.x - row * 3;
            float o = b2[k];
            const float* wr = W2 + (size_t)k * 64;
#pragma unroll 8
            for (int j = 0; j < 64; j++) o = fmaf(mid[row][j], wr[j], o);
            out[(size_t)(b0 + row) * 3 + k] = o;
        }
    }
}

__global__ __launch_bounds__(512, 2)
void lstm_fused_kernel(const float* __restrict__ x,
                       const float* __restrict__ Wih0, const float* __restrict__ Whh0,
                       const float* __restrict__ bih0, const float* __restrict__ bhh0,
                       const float* __restrict__ Wih1, const float* __restrict__ Whh1,
                       const float* __restrict__ bih1, const float* __restrict__ bhh1,
                       unsigned short* __restrict__ h0sq,
                       const float* __restrict__ W1, const float* __restrict__ b1,
                       const float* __restrict__ W2, const float* __restrict__ b2,
                       float* __restrict__ out,
                       int* __restrict__ flags)
{
    const int bt = blockIdx.x & (NTILE - 1);
    if (blockIdx.x < NTILE)
        lstm_body<64,  true >(x, nullptr, Wih0, Whh0, bih0, bhh0, h0sq,
                              W1, b1, W2, b2, out, flags + bt, bt);
    else
        lstm_body<128, false>(nullptr, h0sq, Wih1, Whh1, bih1, bhh1, nullptr,
                              W1, b1, W2, b2, out, flags + bt, bt);
}

extern "C" void kernel_launch(void* const* d_in, const int* in_sizes, int n_in,
                              void* d_out, int out_size, void* d_ws, size_t ws_size,
                              hipStream_t stream) {
    const float* x     = (const float*)d_in[0];
    const float* W_ih0 = (const float*)d_in[1];
    const float* W_hh0 = (const float*)d_in[2];
    const float* b_ih0 = (const float*)d_in[3];
    const float* b_hh0 = (const float*)d_in[4];
    const float* W_ih1 = (const float*)d_in[5];
    const float* W_hh1 = (const float*)d_in[6];
    const float* b_ih1 = (const float*)d_in[7];
    const float* b_hh1 = (const float*)d_in[8];
    const float* W1    = (const float*)d_in[9];
    const float* b1    = (const float*)d_in[10];
    const float* W2    = (const float*)d_in[11];
    const float* b2    = (const float*)d_in[12];
    float* out = (float*)d_out;

    // workspace: h0sq bf16[256*512*128] @0 (32 MB); flags @48 MB (kept at the
    // previously-validated offset)
    char* ws = (char*)d_ws;
    unsigned short* h0sq  = (unsigned short*)ws;
    int*            flags = (int*)(ws + 50331648);

    hipMemsetAsync(flags, 0, NTILE * sizeof(int), stream);  // graph-capturable
    lstm_fused_kernel<<<2 * NTILE, 512, 0, stream>>>(x, W_ih0, W_hh0, b_ih0, b_hh0,
                                                     W_ih1, W_hh1, b_ih1, b_hh1,
                                                     h0sq, W1, b1, W2, b2, out, flags);
}

// Round 9
// 479.824 us; speedup vs baseline: 1.1870x; 1.1870x over previous
//
#include <hip/hip_runtime.h>
#include <hip/hip_bf16.h>
#include <stdint.h>

// Problem dims
#define BATCH 256
#define SEQ   512
#define INDIM 64
#define H     128
#define RB    4               // batch rows per block (valid C-rows at quad*4, r=0)
#define NTILE (BATCH / RB)    // 64 batch tiles per layer
#define CH    16              // pipeline handoff chunk (steps)
#define NCH   (SEQ / CH)

using short8  = __attribute__((ext_vector_type(8))) short;  // 8 bf16 MFMA A/B frag
using float4v = __attribute__((ext_vector_type(4))) float;  // MFMA C/D frag

#define LOG2E 1.4426950408889634f

__device__ __forceinline__ unsigned short f2bf(float f) {
    union { float f; uint32_t u; } v; v.f = f;
    uint32_t u = v.u;
    return (unsigned short)((u + 0x7FFFu + ((u >> 16) & 1u)) >> 16); // RNE
}

__device__ __forceinline__ float fast_exp2(float x) {
#if __has_builtin(__builtin_amdgcn_exp2f)
    return __builtin_amdgcn_exp2f(x);
#else
    return __expf(x * 0.6931471805599453f);
#endif
}
__device__ __forceinline__ float fast_rcp(float x) {
#if __has_builtin(__builtin_amdgcn_rcpf)
    return __builtin_amdgcn_rcpf(x);
#else
    return 1.f / x;
#endif
}
__device__ __forceinline__ float sigmoid_fast(float x) {
    return fast_rcp(1.f + fast_exp2(-LOG2E * x));
}
__device__ __forceinline__ float tanh_fast(float x) {
    return fmaf(-2.f, fast_rcp(1.f + fast_exp2((2.f * LOG2E) * x)), 1.f);
}

// In-step barrier: LDS ordering only (lgkmcnt). Global prefetch loads and
// producer h-stores stay in flight across it. Full __syncthreads (vmcnt
// drain) only at producer chunk boundaries.
__device__ __forceinline__ void light_barrier() {
    asm volatile("s_waitcnt lgkmcnt(0)\n\ts_barrier" ::: "memory");
}

// ---------------- x fp32 -> bf16 convert (+ flag zeroing) ----------------
// R8 lesson: the f32->bf16 cvt CANNOT live in the producer's per-step reload
// path — the dependent v_cvt forces a mid-step vmcnt drain (+600cy/step).
// The standalone conv kernel is restored (R5 structure).
__global__ void conv_x_kernel(const float* __restrict__ x,
                              unsigned short* __restrict__ xb, int n4,
                              int* __restrict__ flags) {
    int i = blockIdx.x * blockDim.x + threadIdx.x;
    if (blockIdx.x == 0 && threadIdx.x < NTILE) flags[threadIdx.x] = 0;
    if (i >= n4) return;
    float4 f = ((const float4*)x)[i];
    ushort4 o;
    o.x = f2bf(f.x); o.y = f2bf(f.y); o.z = f2bf(f.z); o.w = f2bf(f.w);
    ((ushort4*)xb)[i] = o;
}

// ---------------- fused 2-layer pipelined LSTM + head ----------------
// 128 blocks x 512 threads (R5 skeleton = 407-410us verified). Blocks
// 0..63: layer0 (producer), 64..127: layer1 (consumer), paired on batch
// tile bt via chunked flag handoff through global h0sq.
//
// Established constraints:
//  - R2/R7: occupancy & wave-width moves dead (weights force 2 waves/SIMD).
//  - R3 (verified): depth-2 h-MFMA chains. R4: consumer x reload dist >= 2.
//  - R8: producer must consume PRE-CONVERTED bf16 x (no cvt in step path).
//  - Model: consumer step ~1860cy = ~1030cy SIMD matrix-pipe time (2 waves x
//    32 MFMA x 16cy) + ~800cy unhidden latency.
//
// R9 change (single mechanism, untested half of R8): consumer split-pipeline.
//  - step head: accB = x2+x3 only (8 MFMAs, 128cy — fits fully under the
//    ~150cy ds_read window; R5's 16-MFMA head overflowed it ~100cy).
//  - step tail: pA(bias+x0+x1) for step t+1 issued BETWEEN gate extraction
//    and the activation chain — MFMA pipe fed while activation runs on
//    VALU/trans. pA persists across the barrier (+16 regs, no spill per R8).
//  - accumulation order per chain unchanged -> bit-identical to R5.
// Producer: R5 step verbatim. R5 lesson: all register arrays statically
// indexed; double buffers statically named.
template<int KIN, bool IS_PROD>
__device__ __forceinline__ void lstm_body(
    const unsigned short* __restrict__ xin,  // [BATCH][SEQ][KIN] bf16
    const float* __restrict__ Wih,           // [4H][KIN]
    const float* __restrict__ Whh,           // [4H][H]
    const float* __restrict__ b_ih, const float* __restrict__ b_hh,
    unsigned short* __restrict__ outseq,     // producer: [BATCH][SEQ][H] bf16
    const float* __restrict__ W1, const float* __restrict__ b1,
    const float* __restrict__ W2, const float* __restrict__ b2,
    float* __restrict__ out,                 // consumer: [BATCH][3]
    int* flag, int bt)
{
    constexpr int KT  = KIN / 32;
    constexpr int PAD = 132;                 // 66 dwords == 2 mod 32 -> 2-way (free) aliasing
    const int lane = threadIdx.x & 63;
    const int quad = lane >> 4;
    const int l16  = lane & 15;
    const int b0   = bt * RB;
    const int cell = (threadIdx.x >> 6) * 16 + l16;
    const int arow = l16 & 12;               // LDS h row this lane reads (4-lane broadcast)
    const int xrow = b0 + (l16 >> 2);        // batch row this lane loads (duplicated 4x)

    __shared__ short hbuf[2][16][PAD];
    __shared__ float hl[RB][128];            // fp32 h_last (consumer head input)
    __shared__ float mid[RB][65];
    for (int i = threadIdx.x; i < 2 * 16 * PAD; i += 512) ((short*)hbuf)[i] = 0;

    // ---- weight fragments (loaded once, fp32->bf16, persist in registers) ----
    short8 whh_f[4][4];
    short8 wih_f[4][KT];
    float  bias[4];
#pragma unroll
    for (int tT = 0; tT < 4; tT++) {
        const int n = tT * 128 + cell;
#pragma unroll
        for (int kt = 0; kt < 4; kt++) {
            const float* p = Whh + (size_t)n * H + kt * 32 + quad * 8;
            float4 f0 = *(const float4*)p;
            float4 f1 = *(const float4*)(p + 4);
            short8 s;
            s[0]=f2bf(f0.x); s[1]=f2bf(f0.y); s[2]=f2bf(f0.z); s[3]=f2bf(f0.w);
            s[4]=f2bf(f1.x); s[5]=f2bf(f1.y); s[6]=f2bf(f1.z); s[7]=f2bf(f1.w);
            whh_f[tT][kt] = s;
        }
#pragma unroll
        for (int kt = 0; kt < KT; kt++) {
            const float* p = Wih + (size_t)n * KIN + kt * 32 + quad * 8;
            float4 f0 = *(const float4*)p;
            float4 f1 = *(const float4*)(p + 4);
            short8 s;
            s[0]=f2bf(f0.x); s[1]=f2bf(f0.y); s[2]=f2bf(f0.z); s[3]=f2bf(f0.w);
            s[4]=f2bf(f1.x); s[5]=f2bf(f1.y); s[6]=f2bf(f1.z); s[7]=f2bf(f1.w);
            wih_f[tT][kt] = s;
        }
        bias[tT] = b_ih[n] + b_hh[n];
    }

    // ---- persistent seed registers (R5) ----
    float4v bias4[4], zero4;
#pragma unroll
    for (int tT = 0; tT < 4; tT++)
        bias4[tT] = (float4v){bias[tT], bias[tT], bias[tT], bias[tT]};
    zero4 = (float4v){0.f, 0.f, 0.f, 0.f};
    asm volatile("" : "+v"(bias4[0]), "+v"(bias4[1]), "+v"(bias4[2]),
                      "+v"(bias4[3]), "+v"(zero4));

    float c0 = 0.f;                          // this lane's single cell state

    const unsigned short* xp = xin + ((size_t)xrow * SEQ) * KIN + quad * 8;
    unsigned short* op = nullptr;
    if (IS_PROD)
        op = outseq + ((size_t)(b0 + quad) * SEQ) * H + cell;

    short8 xf0[KT], xf1[KT];                 // statically-named x double buffer
    __syncthreads();                         // hbuf zero-init visible

    if constexpr (IS_PROD) {
        // ================= producer: R5 step verbatim ======================
        auto pstep = [&](int t, int CUR, short8 (&xf)[KT],
                         bool doPre) __attribute__((always_inline)) {
            short8 ha[4];
#pragma unroll
            for (int kt = 0; kt < 4; kt++)
                ha[kt] = *(const short8*)&hbuf[CUR][arow][kt * 32 + quad * 8];

            float4v accA[4], accB[4];
#pragma unroll
            for (int tT = 0; tT < 4; tT++)
                accA[tT] = __builtin_amdgcn_mfma_f32_16x16x32_bf16(xf[0], wih_f[tT][0], bias4[tT], 0, 0, 0);
#pragma unroll
            for (int tT = 0; tT < 4; tT++)
                accA[tT] = __builtin_amdgcn_mfma_f32_16x16x32_bf16(xf[1], wih_f[tT][1], accA[tT], 0, 0, 0);
            if (doPre) {                     // reload xf = x(t+2) (WAR after use)
                const unsigned short* p = xp + (size_t)(t + 2) * KIN;
#pragma unroll
                for (int kt = 0; kt < KT; kt++) xf[kt] = *(const short8*)(p + kt * 32);
            }
#pragma unroll
            for (int tT = 0; tT < 4; tT++)
                accA[tT] = __builtin_amdgcn_mfma_f32_16x16x32_bf16(ha[0], whh_f[tT][0], accA[tT], 0, 0, 0);
#pragma unroll
            for (int tT = 0; tT < 4; tT++)
                accB[tT] = __builtin_amdgcn_mfma_f32_16x16x32_bf16(ha[2], whh_f[tT][2], zero4, 0, 0, 0);
#pragma unroll
            for (int tT = 0; tT < 4; tT++)
                accA[tT] = __builtin_amdgcn_mfma_f32_16x16x32_bf16(ha[1], whh_f[tT][1], accA[tT], 0, 0, 0);
#pragma unroll
            for (int tT = 0; tT < 4; tT++)
                accB[tT] = __builtin_amdgcn_mfma_f32_16x16x32_bf16(ha[3], whh_f[tT][3], accB[tT], 0, 0, 0);

            float g0 = accA[0][0] + accB[0][0];
            float g1 = accA[1][0] + accB[1][0];
            float g2 = accA[2][0] + accB[2][0];
            float g3 = accA[3][0] + accB[3][0];

            float si = sigmoid_fast(g0);
            float sf = sigmoid_fast(g1);
            float tg = tanh_fast(g2);
            float so = sigmoid_fast(g3);
            c0 = fmaf(sf, c0, si * tg);
            float h = so * tanh_fast(c0);
            uint32_t hp;
            asm("v_cvt_pk_bf16_f32 %0, %1, %2" : "=v"(hp) : "v"(h), "v"(h));
            hbuf[CUR ^ 1][quad * 4][cell] = (short)(hp & 0xffffu);
            *op = (unsigned short)(hp & 0xffffu);  // fire-and-forget
            op += H;
            light_barrier();
        };

        // one-time fill: x(0), x(1)
#pragma unroll
        for (int kt = 0; kt < KT; kt++) {
            xf0[kt] = *(const short8*)(xp + kt * 32);
            xf1[kt] = *(const short8*)(xp + KIN + kt * 32);
        }
        for (int ch = 0; ch < NCH; ch++) {
            const int t0 = ch * CH;
#pragma unroll 1
            for (int i = 0; i < CH; i += 2) {
                const int t = t0 + i;
                pstep(t,     0, xf0, t + 2 < SEQ);
                pstep(t + 1, 1, xf1, t + 3 < SEQ);
            }
            __syncthreads();                 // vmcnt drain (h0sq stores) for release
            if (threadIdx.x == 0)
                __hip_atomic_fetch_add(flag, 1, __ATOMIC_RELEASE, __HIP_MEMORY_SCOPE_AGENT);
        }
    } else {
        // ================= consumer: split-pipeline step (R9) ==============
        // pA persists across the barrier: bias + x0 + x1 of the NEXT step,
        // computed during the activation tail while the MFMA pipe is idle.
        float4v pA[4];

        auto cstep = [&](int t, int CUR, short8 (&xfC)[KT], short8 (&xfN)[KT],
                         bool doPre, bool doNext) __attribute__((always_inline)) {
            short8 ha[4];
#pragma unroll
            for (int kt = 0; kt < 4; kt++)
                ha[kt] = *(const short8*)&hbuf[CUR][arow][kt * 32 + quad * 8];

            float4v accB[4];                 // head: only x2,x3 (8 MFMAs < ds_read window)
#pragma unroll
            for (int tT = 0; tT < 4; tT++)
                accB[tT] = __builtin_amdgcn_mfma_f32_16x16x32_bf16(xfC[2], wih_f[tT][2], zero4, 0, 0, 0);
#pragma unroll
            for (int tT = 0; tT < 4; tT++)
                accB[tT] = __builtin_amdgcn_mfma_f32_16x16x32_bf16(xfC[3], wih_f[tT][3], accB[tT], 0, 0, 0);
            if (doPre) {                     // reload xfC = x(t+2) (WAR; dist-2 kept)
                const unsigned short* p = xp + (size_t)(t + 2) * KIN;
#pragma unroll
                for (int kt = 0; kt < KT; kt++) xfC[kt] = *(const short8*)(p + kt * 32);
            }
            // recurrent projection: two parallel depth-2 chains
#pragma unroll
            for (int tT = 0; tT < 4; tT++)
                pA[tT] = __builtin_amdgcn_mfma_f32_16x16x32_bf16(ha[0], whh_f[tT][0], pA[tT], 0, 0, 0);
#pragma unroll
            for (int tT = 0; tT < 4; tT++)
                accB[tT] = __builtin_amdgcn_mfma_f32_16x16x32_bf16(ha[2], whh_f[tT][2], accB[tT], 0, 0, 0);
#pragma unroll
            for (int tT = 0; tT < 4; tT++)
                pA[tT] = __builtin_amdgcn_mfma_f32_16x16x32_bf16(ha[1], whh_f[tT][1], pA[tT], 0, 0, 0);
#pragma unroll
            for (int tT = 0; tT < 4; tT++)
                accB[tT] = __builtin_amdgcn_mfma_f32_16x16x32_bf16(ha[3], whh_f[tT][3], accB[tT], 0, 0, 0);

            float g0 = pA[0][0] + accB[0][0];
            float g1 = pA[1][0] + accB[1][0];
            float g2 = pA[2][0] + accB[2][0];
            float g3 = pA[3][0] + accB[3][0];

            // refill pA for t+1 NOW: these 8 MFMAs run under the activation
            if (doNext) {
#pragma unroll
                for (int tT = 0; tT < 4; tT++)
                    pA[tT] = __builtin_amdgcn_mfma_f32_16x16x32_bf16(xfN[0], wih_f[tT][0], bias4[tT], 0, 0, 0);
#pragma unroll
                for (int tT = 0; tT < 4; tT++)
                    pA[tT] = __builtin_amdgcn_mfma_f32_16x16x32_bf16(xfN[1], wih_f[tT][1], pA[tT], 0, 0, 0);
            }

            float si = sigmoid_fast(g0);
            float sf = sigmoid_fast(g1);
            float tg = tanh_fast(g2);
            float so = sigmoid_fast(g3);
            c0 = fmaf(sf, c0, si * tg);
            float h = so * tanh_fast(c0);
            uint32_t hp;
            asm("v_cvt_pk_bf16_f32 %0, %1, %2" : "=v"(hp) : "v"(h), "v"(h));
            hbuf[CUR ^ 1][quad * 4][cell] = (short)(hp & 0xffffu);
            if (t == SEQ - 1) hl[quad][cell] = h;
            light_barrier();
        };

        for (int ch = 0; ch < NCH; ch++) {
            const int t0 = ch * CH;
            if (threadIdx.x == 0) {
                while (__hip_atomic_load(flag, __ATOMIC_RELAXED, __HIP_MEMORY_SCOPE_AGENT) <= ch)
                    __builtin_amdgcn_s_sleep(2);
                (void)__hip_atomic_load(flag, __ATOMIC_ACQUIRE, __HIP_MEMORY_SCOPE_AGENT);
            }
            __syncthreads();
            // chunk fill: x(t0), x(t0+1) + pA for step t0 (R5-equivalent cost:
            // first-step x-MFMAs always waited on these loads)
            {
                const unsigned short* p0 = xp + (size_t)t0 * KIN;
                const unsigned short* p1 = p0 + KIN;
#pragma unroll
                for (int kt = 0; kt < KT; kt++) {
                    xf0[kt] = *(const short8*)(p0 + kt * 32);
                    xf1[kt] = *(const short8*)(p1 + kt * 32);
                }
#pragma unroll
                for (int tT = 0; tT < 4; tT++)
                    pA[tT] = __builtin_amdgcn_mfma_f32_16x16x32_bf16(xf0[0], wih_f[tT][0], bias4[tT], 0, 0, 0);
#pragma unroll
                for (int tT = 0; tT < 4; tT++)
                    pA[tT] = __builtin_amdgcn_mfma_f32_16x16x32_bf16(xf0[1], wih_f[tT][1], pA[tT], 0, 0, 0);
            }

#pragma unroll 1
            for (int i = 0; i < CH; i += 2) {
                const int t = t0 + i;
                // even: xfC=xf0 (x(t)), xfN=xf1 (x(t+1), always in-chunk)
                cstep(t,     0, xf0, xf1, i + 2 < CH, true);
                // odd: xfC=xf1 (x(t+1)), xfN=xf0 (x(t+2), reloaded mid even step)
                cstep(t + 1, 1, xf1, xf0, i + 3 < CH, i + 2 < CH);
            }
        }

        // ---- MLP head for this block's RB rows (hl visible via last barrier)
        if (threadIdx.x < RB * 64) {
            const int row = threadIdx.x >> 6, j = threadIdx.x & 63;
            float s = b1[j];
            const float* wr = W1 + (size_t)j * 128;
#pragma unroll 8
            for (int k = 0; k < 128; k++) s = fmaf(hl[row][k], wr[k], s);
            mid[row][j] = fmaxf(s, 0.f);
        }
        __syncthreads();
        if (threadIdx.x < RB * 3) {
            const int row = threadIdx.x / 3, k = threadIdx.x - row * 3;
            float o = b2[k];
            const float* wr = W2 + (size_t)k * 64;
#pragma unroll 8
            for (int j = 0; j < 64; j++) o = fmaf(mid[row][j], wr[j], o);
            out[(size_t)(b0 + row) * 3 + k] = o;
        }
    }
}

__global__ __launch_bounds__(512, 2)
void lstm_fused_kernel(const unsigned short* __restrict__ xb,
                       const float* __restrict__ Wih0, const float* __restrict__ Whh0,
                       const float* __restrict__ bih0, const float* __restrict__ bhh0,
                       const float* __restrict__ Wih1, const float* __restrict__ Whh1,
                       const float* __restrict__ bih1, const float* __restrict__ bhh1,
                       unsigned short* __restrict__ h0sq,
                       const float* __restrict__ W1, const float* __restrict__ b1,
                       const float* __restrict__ W2, const float* __restrict__ b2,
                       float* __restrict__ out,
                       int* __restrict__ flags)
{
    const int bt = blockIdx.x & (NTILE - 1);
    if (blockIdx.x < NTILE)
        lstm_body<64,  true >(xb,   Wih0, Whh0, bih0, bhh0, h0sq,
                              W1, b1, W2, b2, out, flags + bt, bt);
    else
        lstm_body<128, false>(h0sq, Wih1, Whh1, bih1, bhh1, nullptr,
                              W1, b1, W2, b2, out, flags + bt, bt);
}

extern "C" void kernel_launch(void* const* d_in, const int* in_sizes, int n_in,
                              void* d_out, int out_size, void* d_ws, size_t ws_size,
                              hipStream_t stream) {
    const float* x     = (const float*)d_in[0];
    const float* W_ih0 = (const float*)d_in[1];
    const float* W_hh0 = (const float*)d_in[2];
    const float* b_ih0 = (const float*)d_in[3];
    const float* b_hh0 = (const float*)d_in[4];
    const float* W_ih1 = (const float*)d_in[5];
    const float* W_hh1 = (const float*)d_in[6];
    const float* b_ih1 = (const float*)d_in[7];
    const float* b_hh1 = (const float*)d_in[8];
    const float* W1    = (const float*)d_in[9];
    const float* b1    = (const float*)d_in[10];
    const float* W2    = (const float*)d_in[11];
    const float* b2    = (const float*)d_in[12];
    float* out = (float*)d_out;

    // workspace: xb bf16[256*512*64] @0 (16 MB); h0sq bf16[256*512*128] @16 MB (32 MB); flags @48 MB
    char* ws = (char*)d_ws;
    unsigned short* xb    = (unsigned short*)ws;
    unsigned short* h0sq  = (unsigned short*)(ws + 16777216);
    int*            flags = (int*)(ws + 50331648);

    conv_x_kernel<<<8192, 256, 0, stream>>>(x, xb, (BATCH * SEQ * INDIM) / 4, flags);
    lstm_fused_kernel<<<2 * NTILE, 512, 0, stream>>>(xb, W_ih0, W_hh0, b_ih0, b_hh0,
                                                     W_ih1, W_hh1, b_ih1, b_hh1,
                                                     h0sq, W1, b1, W2, b2, out, flags);
}